// Round 2
// baseline (5008.736 us; speedup 1.0000x reference)
//
#include <hip/hip_runtime.h>

// HMGRUV2: 2-layer masked GRU scan. B=256, T=256, L=2, IN=256, H=256 (f32 io).
// Round 6:
//  REVERT round-5's 2-batch/block (1715->2444us REGRESSION: scan is per-step
//  latency-bound at grid=256, not L2-BW-bound; L2 roofline ~1120us is a
//  ceiling we haven't hit). This round attacks per-step serialization:
//   - split-K reduce moved INSIDE the quad: ks=lane&3, j=wave*16+lane>>2;
//     partials reduced with 2 DPP shuffles (xor1/xor2) -- no rbuf LDS
//     round-trip, no partials barrier.
//   - epilogue computed redundantly by all 4 ks-lanes (no 1/4-occupancy
//     phase); only ks==0 lanes store out / update h LDS.
//   - barriers/step: E[3.375] -> E[1.375] (step boundary + h0-visibility
//     only when l0g && b1; double-buffered h makes the rest safe).
//  Weights stay f16-packed in d_ws ([k8][gate][j] uint4 layout, L2-resident).

#define BB 256
#define TT 256
#define HH 256
#define MAT_U32 98304   // u32 words per packed matrix (768*256/2)
#define MAT_U4  24576   // uint4 words per packed matrix
#define NBT 65536       // B*T
#define GI_STRIDE 768

typedef unsigned int u32;
typedef _Float16 f16;
typedef _Float16 f16x2 __attribute__((ext_vector_type(2)));
typedef _Float16 f16x4 __attribute__((ext_vector_type(4)));
typedef _Float16 f16x8 __attribute__((ext_vector_type(8)));
typedef float f32x4 __attribute__((ext_vector_type(4)));

#if defined(__has_builtin)
#  if __has_builtin(__builtin_amdgcn_fdot2)
#    define HAVE_FDOT2 1
#  endif
#endif

__device__ __forceinline__ float dot2(f16x2 a, f16x2 b, float c) {
#ifdef HAVE_FDOT2
    return __builtin_amdgcn_fdot2(a, b, c, false);
#else
    return c + (float)a.x * (float)b.x + (float)a.y * (float)b.y;
#endif
}

union U4 { uint4 u; f16x2 h[4]; f16x8 v; };

__device__ __forceinline__ float sigm(float x) { return 1.0f / (1.0f + __expf(-x)); }
__device__ __forceinline__ float tanhx(float x) { return 1.0f - 2.0f / (__expf(2.0f * x) + 1.0f); }

// quad reduce: sum over the 4 ks lanes (lane^1, lane^2) -- DPP, no LDS
__device__ __forceinline__ float red4(float v) {
    v += __shfl_xor(v, 1);
    v += __shfl_xor(v, 2);
    return v;
}

// ---- pack f32 weights -> f16 pairs (round-3 proven layout) ----
// u32 flat (per matrix m) = k8*3072 + g*1024 + j*4 + q ; k = k8*8 + q*2 (+1).
__global__ void pack_weights(const float* __restrict__ W_ih0,
                             const float* __restrict__ W_hh0,
                             const float* __restrict__ W_ih1,
                             const float* __restrict__ W_hh1,
                             u32* __restrict__ ws) {
    int tid = blockIdx.x * 256 + threadIdx.x;
    if (tid >= 6 * MAT_U32) return;
    int m  = tid / MAT_U32;
    int r  = tid % MAT_U32;
    int k8 = r / 3072;
    int r2 = r % 3072;
    int g  = r2 / 1024;
    int r3 = r2 % 1024;
    int jj = r3 >> 2;
    int q  = r3 & 3;
    int k  = k8 * 8 + q * 2;
    int c  = g * 256 + jj;
    float lo, hi;
    switch (m) {
        case 0: lo = W_ih0[c * 512 + k];       hi = W_ih0[c * 512 + k + 1];   break;
        case 1: lo = W_ih0[c * 512 + 256 + k]; hi = W_ih0[c * 512 + 257 + k]; break;
        case 2: lo = W_hh0[c * 256 + k];       hi = W_hh0[c * 256 + k + 1];   break;
        case 3: lo = W_ih1[c * 512 + k];       hi = W_ih1[c * 512 + k + 1];   break;
        case 4: lo = W_ih1[c * 512 + 256 + k]; hi = W_ih1[c * 512 + 257 + k]; break;
        default: lo = W_hh1[c * 256 + k];      hi = W_hh1[c * 256 + k + 1];   break;
    }
    union { f16x2 h; u32 u; } pk;
    pk.h.x = (f16)lo;
    pk.h.y = (f16)hi;
    ws[tid] = pk.u;
}

// ---- MFMA GEMM: gi[layer][bt][m] = sum_k W_ihLx[m][k] * x[bt][k]  (f16) ----
__global__ __launch_bounds__(256, 2) void proj_gemm(
    const float* __restrict__ x0, const float* __restrict__ x1,
    const uint4* __restrict__ Wt, f16* __restrict__ gi) {
    const int nblk  = blockIdx.x & 1023;
    const int layer = blockIdx.x >> 10;
    const int bt0   = nblk * 64;
    const float4* __restrict__ X4 = (const float4*)(layer ? x1 : x0);
    const uint4*  __restrict__ W  = Wt + (layer ? 3 : 0) * MAT_U4;
    f16* __restrict__ giL = gi + (size_t)layer * NBT * GI_STRIDE;

    __shared__ __align__(16) f16 xs[64 * 264];  // 64 rows x 256 f16, +8 pad

    const int tid = threadIdx.x;
    for (int it = 0; it < 16; ++it) {
        int idx = it * 256 + tid;
        int r = idx >> 6, c4 = idx & 63;
        float4 v = X4[(size_t)(bt0 + r) * 64 + c4];
        union { f16x4 h; unsigned long long u; } pk;
        pk.h = (f16x4){(f16)v.x, (f16)v.y, (f16)v.z, (f16)v.w};
        *(unsigned long long*)((char*)xs + r * 528 + c4 * 8) = pk.u;
    }
    __syncthreads();

    const int wave = tid >> 6;
    const int lane = tid & 63;
    const int l16  = lane & 15;
    const int quad = lane >> 4;

    for (int i = 0; i < 12; ++i) {
        const int mt = i * 4 + wave;   // m-tile 0..47
        const int m0 = mt * 16;
        const int g  = m0 >> 8;
        const int j0 = m0 & 255;
        f16x8 afr[8];
#pragma unroll
        for (int kst = 0; kst < 8; ++kst) {
            U4 a;
            a.u = W[((kst * 4 + quad) * 3 + g) * 256 + (j0 + l16)];
            afr[kst] = a.v;
        }
#pragma unroll
        for (int nt = 0; nt < 4; ++nt) {
            const int n0 = nt * 16;
            f32x4 acc = {0.f, 0.f, 0.f, 0.f};
#pragma unroll
            for (int kst = 0; kst < 8; ++kst) {
                f16x8 bfr = *(const f16x8*)((const char*)xs +
                               (n0 + l16) * 528 + kst * 64 + quad * 16);
                acc = __builtin_amdgcn_mfma_f32_16x16x32_f16(afr[kst], bfr, acc, 0, 0, 0);
            }
            const int col = bt0 + n0 + l16;
            union { f16x4 h; unsigned long long u; } o;
            o.h = (f16x4){(f16)acc[0], (f16)acc[1], (f16)acc[2], (f16)acc[3]};
            *(unsigned long long*)(giL + (size_t)col * GI_STRIDE + m0 + quad * 4) = o.u;
        }
    }
}

// ---- split-K partial GEMV: 8 k8-groups (64 k) for unit j's three gates ----
__device__ __forceinline__ void gemv3p(const uint4* __restrict__ W, int j, int ksb,
                                       const uint4* __restrict__ s4,
                                       float& pr, float& pz, float& pn) {
#pragma unroll 4
    for (int i = 0; i < 8; ++i) {
        const int k8 = ksb + i;
        U4 sv, wr, wz, wn;
        sv.u = s4[k8];
        wr.u = W[(k8 * 3 + 0) * 256 + j];
        wz.u = W[(k8 * 3 + 1) * 256 + j];
        wn.u = W[(k8 * 3 + 2) * 256 + j];
#pragma unroll
        for (int q = 0; q < 4; ++q) {
            pr = dot2(wr.h[q], sv.h[q], pr);
            pz = dot2(wz.h[q], sv.h[q], pz);
            pn = dot2(wn.h[q], sv.h[q], pn);
        }
    }
}

template <bool PRECOMP>
__global__ __launch_bounds__(1024, 4) void hmgru_scan(
    const float* __restrict__ x0, const float* __restrict__ x1,
    const float* __restrict__ hx0, const float* __restrict__ hx1,
    const float* __restrict__ b_ih0, const float* __restrict__ b_hh0,
    const float* __restrict__ b_ih1, const float* __restrict__ b_hh1,
    const int* __restrict__ dx, const int* __restrict__ dxlz,
    const uint4* __restrict__ Wt, const f16* __restrict__ gi,
    float* __restrict__ out) {
    const int b   = blockIdx.x;
    const int tid = threadIdx.x;
    const int wv  = tid >> 6;              // wave 0..15
    const int ln  = tid & 63;
    const int ks  = ln & 3;                // k-slice, quad-local (DPP reduce)
    const int ksb = ks * 8;
    const int j   = (wv << 4) | (ln >> 2); // hidden unit 0..255

    const uint4* W_ih0x = Wt + 0 * MAT_U4;
    const uint4* W_ih0h = Wt + 1 * MAT_U4;
    const uint4* W_hh0  = Wt + 2 * MAT_U4;
    const uint4* W_ih1x = Wt + 3 * MAT_U4;
    const uint4* W_ih1h = Wt + 4 * MAT_U4;
    const uint4* W_hh1  = Wt + 5 * MAT_U4;
    const f16* gi0 = gi;
    const f16* gi1 = gi + (size_t)NBT * GI_STRIDE;

    __shared__ __align__(16) f16 h0s[2][256], h1s[2][256];
    __shared__ __align__(16) f16 x0sh[2][256], x1sh[2][256];  // fallback only
    __shared__ int m0s[TT], mAs[TT], mBs[TT];

    // biases: fold r/z into sums; n-gate needs ih/hh parts separate
    const float sb0r = b_ih0[j] + b_hh0[j];
    const float sb0z = b_ih0[256 + j] + b_hh0[256 + j];
    const float bi0n = b_ih0[512 + j], bh0n = b_hh0[512 + j];
    const float sb1r = b_ih1[j] + b_hh1[j];
    const float sb1z = b_ih1[256 + j] + b_hh1[256 + j];
    const float bi1n = b_ih1[512 + j], bh1n = b_hh1[512 + j];

    // (b1=0, dd1=1): bias-only GRU constant.
    const float c1r = sigm(sb1r);
    const float c1z = sigm(sb1z);
    const float c1n = tanhx(bi1n + c1r * bh1n);
    const float c1v = (1.0f - c1z) * c1n;

    float h0reg = hx0[b * HH + j];
    float h1reg = hx1[b * HH + j];

    const int* dxb  = dx + b * 2 * TT;
    const int* dlzb = dxlz + b * TT;
    const float* x0b = x0 + (size_t)b * TT * 256;
    const float* x1b = x1 + (size_t)b * TT * 256;
    float* out0 = out + (size_t)b * TT * HH;
    float* out1 = out + (size_t)(BB + b) * TT * HH;

    if (ks == 0) {
        h0s[0][j] = (f16)h0reg;
        h1s[0][j] = (f16)h1reg;
        if (!PRECOMP) {
            x0sh[0][j] = (f16)x0b[j];
            x1sh[0][j] = (f16)x1b[j];
        }
    }
    if (tid < TT) {
        m0s[tid] = dlzb[tid];
        mAs[tid] = dxb[tid];
        mBs[tid] = dxb[TT + tid];
    }
    __syncthreads();

    int p = 0;
    for (int t = 0; t < TT; ++t) {
        const int b0  = m0s[t];
        const int b1  = mAs[t];
        const int dd0 = t ? mAs[t - 1] : 0;
        const int dd1 = t ? mBs[t - 1] : 0;
        const int bt  = b * TT + t;

        // fallback: prefetch x(t+1) into the other buffer
        if (!PRECOMP && ks == 0 && (t + 1) < TT) {
            x0sh[p ^ 1][j] = (f16)x0b[(t + 1) * 256 + j];
            x1sh[p ^ 1][j] = (f16)x1b[(t + 1) * 256 + j];
        }
        // precomp: ks==0 lane prefetches gi row; folded into pre-reduce partial
        float g0r = 0.f, g0z = 0.f, g0n = 0.f, g1r = 0.f, g1z = 0.f, g1n = 0.f;
        if (PRECOMP && ks == 0) {
            if (b0) {
                const f16* pg = gi0 + (size_t)bt * GI_STRIDE;
                g0r = (float)pg[j]; g0z = (float)pg[256 + j]; g0n = (float)pg[512 + j];
            }
            if (b1) {
                const f16* pg = gi1 + (size_t)bt * GI_STRIDE;
                g1r = (float)pg[j]; g1z = (float)pg[256 + j]; g1n = (float)pg[512 + j];
            }
        }

        // ---------------- Layer 0 ----------------
        const int l0g = b0 | dd0;
        float h0n;
        if (l0g) {
            float pr = 0.f, pz = 0.f, pin = 0.f, phn = 0.f;
            if (!PRECOMP && b0) gemv3p(W_ih0x, j, ksb, (const uint4*)x0sh[p], pr, pz, pin);
            if (dd0)            gemv3p(W_ih0h, j, ksb, (const uint4*)h1s[p], pr, pz, pin);
            if (!dd0)           gemv3p(W_hh0,  j, ksb, (const uint4*)h0s[p], pr, pz, phn);
            pr += g0r; pz += g0z; pin += g0n;   // gi folded once (ks==0 lane)
            pr  = red4(pr);
            pz  = red4(pz);
            pin = red4(pin);
            phn = red4(phn);
            const float r = sigm(pr + sb0r);
            const float z = sigm(pz + sb0z);
            const float n = tanhx(pin + bi0n + r * (phn + bh0n));
            const float h0cur = dd0 ? 0.0f : h0reg;
            h0n = (1.0f - z) * n + z * h0cur;
        } else {
            h0n = h0reg;  // pure carry
        }
        if (ks == 0) {
            out0[t * HH + j] = h0n;
            h0s[p ^ 1][j] = (f16)h0n;
        }
        h0reg = h0n;

        // h0 visibility barrier only when layer-0 recomputed h0 AND layer-1
        // consumes it this step. Otherwise layer-1 reads the old buffer and
        // the h0s[p^1] copy becomes visible at the step-boundary barrier.
        if (l0g & b1) __syncthreads();
        const f16* h0src = l0g ? h0s[p ^ 1] : h0s[p];

        // ---------------- Layer 1 ----------------
        float h1n;
        if (b1) {
            float pr = 0.f, pz = 0.f, pin = 0.f, phn = 0.f;
            if (!PRECOMP) gemv3p(W_ih1x, j, ksb, (const uint4*)x1sh[p], pr, pz, pin);
            gemv3p(W_ih1h, j, ksb, (const uint4*)h0src, pr, pz, pin);
            if (!dd1) gemv3p(W_hh1, j, ksb, (const uint4*)h1s[p], pr, pz, phn);
            pr += g1r; pz += g1z; pin += g1n;
            pr  = red4(pr);
            pz  = red4(pz);
            pin = red4(pin);
            phn = red4(phn);
            const float r = sigm(pr + sb1r);
            const float z = sigm(pz + sb1z);
            const float n = tanhx(pin + bi1n + r * (phn + bh1n));
            const float h1cur = dd1 ? 0.0f : h1reg;
            h1n = (1.0f - z) * n + z * h1cur;
        } else {
            h1n = dd1 ? c1v : h1reg;
        }
        if (ks == 0) {
            out1[t * HH + j] = h1n;
            h1s[p ^ 1][j] = (f16)h1n;
        }
        h1reg = h1n;
        __syncthreads();  // step boundary: new h1 (and h0 copy) visible
        p ^= 1;
    }
}

extern "C" void kernel_launch(void* const* d_in, const int* in_sizes, int n_in,
                              void* d_out, int out_size, void* d_ws, size_t ws_size,
                              hipStream_t stream) {
    const float* x0    = (const float*)d_in[0];
    const float* x1    = (const float*)d_in[1];
    const float* hx0   = (const float*)d_in[2];
    const float* hx1   = (const float*)d_in[3];
    const float* W_ih0 = (const float*)d_in[4];
    const float* W_hh0 = (const float*)d_in[5];
    const float* b_ih0 = (const float*)d_in[6];
    const float* b_hh0 = (const float*)d_in[7];
    const float* W_ih1 = (const float*)d_in[8];
    const float* W_hh1 = (const float*)d_in[9];
    const float* b_ih1 = (const float*)d_in[10];
    const float* b_hh1 = (const float*)d_in[11];
    const int* dx      = (const int*)d_in[12];
    const int* dxlz    = (const int*)d_in[13];
    float* out = (float*)d_out;

    const size_t sz_w  = (size_t)6 * MAT_U32 * sizeof(u32);         // 2.36 MB
    const size_t sz_gi = (size_t)2 * NBT * GI_STRIDE * sizeof(f16); // 201.3 MB
    const bool precomp = (d_ws != nullptr) && (ws_size >= sz_w + sz_gi);

    u32* ws = (u32*)d_ws;
    const int total = 6 * MAT_U32;
    pack_weights<<<(total + 255) / 256, 256, 0, stream>>>(W_ih0, W_hh0, W_ih1, W_hh1, ws);

    f16* gi = (f16*)((char*)d_ws + sz_w);
    if (precomp) {
        proj_gemm<<<2048, 256, 0, stream>>>(x0, x1, (const uint4*)ws, gi);
        hmgru_scan<true><<<BB, 1024, 0, stream>>>(
            x0, x1, hx0, hx1, b_ih0, b_hh0, b_ih1, b_hh1, dx, dxlz,
            (const uint4*)ws, gi, out);
    } else {
        hmgru_scan<false><<<BB, 1024, 0, stream>>>(
            x0, x1, hx0, hx1, b_ih0, b_hh0, b_ih1, b_hh1, dx, dxlz,
            (const uint4*)ws, gi, out);
    }
}

// Round 3
// 2744.628 us; speedup vs baseline: 1.8249x; 1.8249x over previous
//
#include <hip/hip_runtime.h>

// HMGRUV2: 2-layer masked GRU scan. B=256, T=256, L=2, IN=256, H=256 (f32 io).
// Round 7: REVERT to round-4 structure (proven 1715us; R5 2-batch=2444us and
// R6 quad-split=4913us both regressed — R6 counters: 5e7 LDS bank conflicts
// from ks=lane&3 state reads). Round-4 lane layout restored: j=tid&255,
// ks=tid>>8 (broadcast LDS state reads, contiguous weight loads, rbuf reduce).
// New this round — attack the barrier drains (per m97: __syncthreads =
// s_waitcnt vmcnt(0) lgkmcnt(0) + s_barrier; this kernel has NO cross-thread
// global communication, so the vmcnt(0) drain is pure waste):
//  (a) all barriers -> lgkm-only (asm s_waitcnt lgkmcnt(0); s_barrier):
//      weight/gi loads stay in flight across phase boundaries.
//  (b) B2 (post-epilogue0) now conditional on b1.
//  (c) W_hh1@h1prev hoisted into phase-0 (independent of h0new; rbuf 9 slots);
//      W_ih1h first 3 k8-groups register-prefetched (pf[9]) in phase-0,
//      consumed in phase-1 -> fills the L2-idle epilogue-0 window.

#define BB 256
#define TT 256
#define HH 256
#define MAT_U32 98304   // u32 words per packed matrix (768*256/2)
#define MAT_U4  24576   // uint4 words per packed matrix
#define NBT 65536       // B*T
#define GI_STRIDE 768

typedef unsigned int u32;
typedef _Float16 f16;
typedef _Float16 f16x2 __attribute__((ext_vector_type(2)));
typedef _Float16 f16x4 __attribute__((ext_vector_type(4)));
typedef _Float16 f16x8 __attribute__((ext_vector_type(8)));
typedef float f32x4 __attribute__((ext_vector_type(4)));

#if defined(__has_builtin)
#  if __has_builtin(__builtin_amdgcn_fdot2)
#    define HAVE_FDOT2 1
#  endif
#endif

// LDS-only barrier: do NOT drain vmcnt (global loads keep flowing; compiler
// still auto-waits vmcnt before any use of a load result).
#define BARRIER_LGKM() asm volatile("s_waitcnt lgkmcnt(0)\n\ts_barrier" ::: "memory")

__device__ __forceinline__ float dot2(f16x2 a, f16x2 b, float c) {
#ifdef HAVE_FDOT2
    return __builtin_amdgcn_fdot2(a, b, c, false);
#else
    return c + (float)a.x * (float)b.x + (float)a.y * (float)b.y;
#endif
}

union U4 { uint4 u; f16x2 h[4]; f16x8 v; };

__device__ __forceinline__ float sigm(float x) { return 1.0f / (1.0f + __expf(-x)); }
__device__ __forceinline__ float tanhx(float x) { return 1.0f - 2.0f / (__expf(2.0f * x) + 1.0f); }

// ---- pack f32 weights -> f16 pairs (round-3 proven layout) ----
// u32 flat (per matrix m) = k8*3072 + g*1024 + j*4 + q ; k = k8*8 + q*2 (+1).
__global__ void pack_weights(const float* __restrict__ W_ih0,
                             const float* __restrict__ W_hh0,
                             const float* __restrict__ W_ih1,
                             const float* __restrict__ W_hh1,
                             u32* __restrict__ ws) {
    int tid = blockIdx.x * 256 + threadIdx.x;
    if (tid >= 6 * MAT_U32) return;
    int m  = tid / MAT_U32;
    int r  = tid % MAT_U32;
    int k8 = r / 3072;
    int r2 = r % 3072;
    int g  = r2 / 1024;
    int r3 = r2 % 1024;
    int jj = r3 >> 2;
    int q  = r3 & 3;
    int k  = k8 * 8 + q * 2;
    int c  = g * 256 + jj;
    float lo, hi;
    switch (m) {
        case 0: lo = W_ih0[c * 512 + k];       hi = W_ih0[c * 512 + k + 1];   break;
        case 1: lo = W_ih0[c * 512 + 256 + k]; hi = W_ih0[c * 512 + 257 + k]; break;
        case 2: lo = W_hh0[c * 256 + k];       hi = W_hh0[c * 256 + k + 1];   break;
        case 3: lo = W_ih1[c * 512 + k];       hi = W_ih1[c * 512 + k + 1];   break;
        case 4: lo = W_ih1[c * 512 + 256 + k]; hi = W_ih1[c * 512 + 257 + k]; break;
        default: lo = W_hh1[c * 256 + k];      hi = W_hh1[c * 256 + k + 1];   break;
    }
    union { f16x2 h; u32 u; } pk;
    pk.h.x = (f16)lo;
    pk.h.y = (f16)hi;
    ws[tid] = pk.u;
}

// ---- MFMA GEMM: gi[layer][bt][m] = sum_k W_ihLx[m][k] * x[bt][k]  (f16) ----
__global__ __launch_bounds__(256, 2) void proj_gemm(
    const float* __restrict__ x0, const float* __restrict__ x1,
    const uint4* __restrict__ Wt, f16* __restrict__ gi) {
    const int nblk  = blockIdx.x & 1023;
    const int layer = blockIdx.x >> 10;
    const int bt0   = nblk * 64;
    const float4* __restrict__ X4 = (const float4*)(layer ? x1 : x0);
    const uint4*  __restrict__ W  = Wt + (layer ? 3 : 0) * MAT_U4;
    f16* __restrict__ giL = gi + (size_t)layer * NBT * GI_STRIDE;

    __shared__ __align__(16) f16 xs[64 * 264];  // 64 rows x 256 f16, +8 pad

    const int tid = threadIdx.x;
    for (int it = 0; it < 16; ++it) {
        int idx = it * 256 + tid;
        int r = idx >> 6, c4 = idx & 63;
        float4 v = X4[(size_t)(bt0 + r) * 64 + c4];
        union { f16x4 h; unsigned long long u; } pk;
        pk.h = (f16x4){(f16)v.x, (f16)v.y, (f16)v.z, (f16)v.w};
        *(unsigned long long*)((char*)xs + r * 528 + c4 * 8) = pk.u;
    }
    __syncthreads();

    const int wave = tid >> 6;
    const int lane = tid & 63;
    const int l16  = lane & 15;
    const int quad = lane >> 4;

    for (int i = 0; i < 12; ++i) {
        const int mt = i * 4 + wave;   // m-tile 0..47
        const int m0 = mt * 16;
        const int g  = m0 >> 8;
        const int j0 = m0 & 255;
        f16x8 afr[8];
#pragma unroll
        for (int kst = 0; kst < 8; ++kst) {
            U4 a;
            a.u = W[((kst * 4 + quad) * 3 + g) * 256 + (j0 + l16)];
            afr[kst] = a.v;
        }
#pragma unroll
        for (int nt = 0; nt < 4; ++nt) {
            const int n0 = nt * 16;
            f32x4 acc = {0.f, 0.f, 0.f, 0.f};
#pragma unroll
            for (int kst = 0; kst < 8; ++kst) {
                f16x8 bfr = *(const f16x8*)((const char*)xs +
                               (n0 + l16) * 528 + kst * 64 + quad * 16);
                acc = __builtin_amdgcn_mfma_f32_16x16x32_f16(afr[kst], bfr, acc, 0, 0, 0);
            }
            const int col = bt0 + n0 + l16;
            union { f16x4 h; unsigned long long u; } o;
            o.h = (f16x4){(f16)acc[0], (f16)acc[1], (f16)acc[2], (f16)acc[3]};
            *(unsigned long long*)(giL + (size_t)col * GI_STRIDE + m0 + quad * 4) = o.u;
        }
    }
}

// ---- split-K partial GEMV: 8 k8-groups (64 k) for unit j's three gates ----
__device__ __forceinline__ void gemv3p(const uint4* __restrict__ W, int j, int ksb,
                                       const uint4* __restrict__ s4,
                                       float& pr, float& pz, float& pn) {
#pragma unroll 4
    for (int i = 0; i < 8; ++i) {
        const int k8 = ksb + i;
        U4 sv, wr, wz, wn;
        sv.u = s4[k8];
        wr.u = W[(k8 * 3 + 0) * 256 + j];
        wz.u = W[(k8 * 3 + 1) * 256 + j];
        wn.u = W[(k8 * 3 + 2) * 256 + j];
#pragma unroll
        for (int q = 0; q < 4; ++q) {
            pr = dot2(wr.h[q], sv.h[q], pr);
            pz = dot2(wz.h[q], sv.h[q], pz);
            pn = dot2(wn.h[q], sv.h[q], pn);
        }
    }
}

// first 3 k8-groups from prefetched registers (same accumulation order)
__device__ __forceinline__ void gemv3p_pre(const U4* __restrict__ pf, int ksb,
                                           const uint4* __restrict__ s4,
                                           float& pr, float& pz, float& pn) {
#pragma unroll
    for (int i = 0; i < 3; ++i) {
        U4 sv;
        sv.u = s4[ksb + i];
#pragma unroll
        for (int q = 0; q < 4; ++q) {
            pr = dot2(pf[i * 3 + 0].h[q], sv.h[q], pr);
            pz = dot2(pf[i * 3 + 1].h[q], sv.h[q], pz);
            pn = dot2(pf[i * 3 + 2].h[q], sv.h[q], pn);
        }
    }
}

// remaining 5 k8-groups streamed from L2
__device__ __forceinline__ void gemv3p_tail(const uint4* __restrict__ W, int j, int ksb,
                                            const uint4* __restrict__ s4,
                                            float& pr, float& pz, float& pn) {
#pragma unroll
    for (int i = 3; i < 8; ++i) {
        const int k8 = ksb + i;
        U4 sv, wr, wz, wn;
        sv.u = s4[k8];
        wr.u = W[(k8 * 3 + 0) * 256 + j];
        wz.u = W[(k8 * 3 + 1) * 256 + j];
        wn.u = W[(k8 * 3 + 2) * 256 + j];
#pragma unroll
        for (int q = 0; q < 4; ++q) {
            pr = dot2(wr.h[q], sv.h[q], pr);
            pz = dot2(wz.h[q], sv.h[q], pz);
            pn = dot2(wn.h[q], sv.h[q], pn);
        }
    }
}

template <bool PRECOMP>
__global__ __launch_bounds__(1024, 4) void hmgru_scan(
    const float* __restrict__ x0, const float* __restrict__ x1,
    const float* __restrict__ hx0, const float* __restrict__ hx1,
    const float* __restrict__ b_ih0, const float* __restrict__ b_hh0,
    const float* __restrict__ b_ih1, const float* __restrict__ b_hh1,
    const int* __restrict__ dx, const int* __restrict__ dxlz,
    const uint4* __restrict__ Wt, const f16* __restrict__ gi,
    float* __restrict__ out) {
    const int b   = blockIdx.x;
    const int tid = threadIdx.x;
    const int j   = tid & 255;
    const int ks  = tid >> 8;
    const int ksb = ks * 8;

    const uint4* W_ih0x = Wt + 0 * MAT_U4;
    const uint4* W_ih0h = Wt + 1 * MAT_U4;
    const uint4* W_hh0  = Wt + 2 * MAT_U4;
    const uint4* W_ih1x = Wt + 3 * MAT_U4;
    const uint4* W_ih1h = Wt + 4 * MAT_U4;
    const uint4* W_hh1  = Wt + 5 * MAT_U4;
    const f16* gi0 = gi;
    const f16* gi1 = gi + (size_t)NBT * GI_STRIDE;

    __shared__ __align__(16) f16 h0s[2][256], h1s[2][256];
    __shared__ __align__(16) f16 x0sh[2][256], x1sh[2][256];  // fallback only
    __shared__ float rbuf[9 * 4 * 256];   // [c][ks][j]; c0-5 layer partials, c6-8 hh1-early
    __shared__ int m0s[TT], mAs[TT], mBs[TT];

    // biases: fold r/z into sums; n-gate needs ih/hh parts separate
    const float sb0r = b_ih0[j] + b_hh0[j];
    const float sb0z = b_ih0[256 + j] + b_hh0[256 + j];
    const float bi0n = b_ih0[512 + j], bh0n = b_hh0[512 + j];
    const float sb1r = b_ih1[j] + b_hh1[j];
    const float sb1z = b_ih1[256 + j] + b_hh1[256 + j];
    const float bi1n = b_ih1[512 + j], bh1n = b_hh1[512 + j];

    // (b1=0, dd1=1): bias-only GRU constant.
    const float c1r = sigm(sb1r);
    const float c1z = sigm(sb1z);
    const float c1n = tanhx(bi1n + c1r * bh1n);
    const float c1v = (1.0f - c1z) * c1n;

    float h0reg = hx0[b * HH + j];
    float h1reg = hx1[b * HH + j];

    const int* dxb  = dx + b * 2 * TT;
    const int* dlzb = dxlz + b * TT;
    const float* x0b = x0 + (size_t)b * TT * 256;
    const float* x1b = x1 + (size_t)b * TT * 256;
    float* out0 = out + (size_t)b * TT * HH;
    float* out1 = out + (size_t)(BB + b) * TT * HH;

    if (tid < 256) {
        h0s[0][j] = (f16)h0reg;
        h1s[0][j] = (f16)h1reg;
        if (!PRECOMP) {
            x0sh[0][j] = (f16)x0b[j];
            x1sh[0][j] = (f16)x1b[j];
        }
        m0s[j] = dlzb[j];
        mAs[j] = dxb[j];
        mBs[j] = dxb[TT + j];
    }
    BARRIER_LGKM();

    int p = 0;
    for (int t = 0; t < TT; ++t) {
        const int b0  = m0s[t];
        const int b1  = mAs[t];
        const int dd0 = t ? mAs[t - 1] : 0;
        const int dd1 = t ? mBs[t - 1] : 0;
        const int bt  = b * TT + t;

        // fallback: prefetch x(t+1) into the other buffer
        if (!PRECOMP && tid < 256 && (t + 1) < TT) {
            x0sh[p ^ 1][j] = (f16)x0b[(t + 1) * 256 + j];
            x1sh[p ^ 1][j] = (f16)x1b[(t + 1) * 256 + j];
        }
        // precomp: prefetch gi rows into registers (hidden behind GEMVs)
        float g0r = 0.f, g0z = 0.f, g0n = 0.f, g1r = 0.f, g1z = 0.f, g1n = 0.f;
        if (PRECOMP && tid < 256) {
            if (b0) {
                const f16* pg = gi0 + (size_t)bt * GI_STRIDE;
                g0r = (float)pg[j]; g0z = (float)pg[256 + j]; g0n = (float)pg[512 + j];
            }
            if (b1) {
                const f16* pg = gi1 + (size_t)bt * GI_STRIDE;
                g1r = (float)pg[j]; g1z = (float)pg[256 + j]; g1n = (float)pg[512 + j];
            }
        }

        const int l0g  = b0 | dd0;
        const int hh1e = b1 & (dd1 ^ 1);   // W_hh1 hoisted into phase 0

        // ---------------- Phase 0: layer-0 GEMVs + hh1-early + pf ----------------
        U4 pf[9];   // W_ih1h k8-groups ksb..ksb+2, 3 gates (consumed phase 1)
        if (l0g) {
            float pir = 0.f, piz = 0.f, pin = 0.f, phr = 0.f, phz = 0.f, phn = 0.f;
            if (!PRECOMP && b0) gemv3p(W_ih0x, j, ksb, (const uint4*)x0sh[p], pir, piz, pin);
            if (dd0)            gemv3p(W_ih0h, j, ksb, (const uint4*)h1s[p], pir, piz, pin);
            if (!dd0)           gemv3p(W_hh0,  j, ksb, (const uint4*)h0s[p], phr, phz, phn);
            rbuf[(0 * 4 + ks) * 256 + j] = pir;
            rbuf[(1 * 4 + ks) * 256 + j] = piz;
            rbuf[(2 * 4 + ks) * 256 + j] = pin;
            rbuf[(3 * 4 + ks) * 256 + j] = phr;
            rbuf[(4 * 4 + ks) * 256 + j] = phz;
            rbuf[(5 * 4 + ks) * 256 + j] = phn;
        }
        if (hh1e) {
            float qhr = 0.f, qhz = 0.f, qhn = 0.f;
            gemv3p(W_hh1, j, ksb, (const uint4*)h1s[p], qhr, qhz, qhn);
            rbuf[(6 * 4 + ks) * 256 + j] = qhr;
            rbuf[(7 * 4 + ks) * 256 + j] = qhz;
            rbuf[(8 * 4 + ks) * 256 + j] = qhn;
        }
        if (b1) {
#pragma unroll
            for (int i = 0; i < 3; ++i) {
                const int k8 = ksb + i;
                pf[i * 3 + 0].u = W_ih1h[(k8 * 3 + 0) * 256 + j];
                pf[i * 3 + 1].u = W_ih1h[(k8 * 3 + 1) * 256 + j];
                pf[i * 3 + 2].u = W_ih1h[(k8 * 3 + 2) * 256 + j];
            }
        }
        if (l0g) BARRIER_LGKM();   // B1: layer-0 partials visible

        // ---------------- Epilogue 0 ----------------
        if (tid < 256) {
            float h0n;
            if (!l0g) {
                h0n = h0reg;  // pure carry
            } else {
                float air = g0r, aiz = g0z, ain = g0n;
                float ahr = 0.f, ahz = 0.f, ahn = 0.f;
#pragma unroll
                for (int s = 0; s < 4; ++s) {
                    air += rbuf[(0 * 4 + s) * 256 + j];
                    aiz += rbuf[(1 * 4 + s) * 256 + j];
                    ain += rbuf[(2 * 4 + s) * 256 + j];
                    ahr += rbuf[(3 * 4 + s) * 256 + j];
                    ahz += rbuf[(4 * 4 + s) * 256 + j];
                    ahn += rbuf[(5 * 4 + s) * 256 + j];
                }
                const float h0cur = dd0 ? 0.0f : h0reg;
                const float r = sigm(air + ahr + sb0r);
                const float z = sigm(aiz + ahz + sb0z);
                const float n = tanhx(ain + bi0n + r * (ahn + bh0n));
                h0n = (1.0f - z) * n + z * h0cur;
            }
            out0[t * HH + j] = h0n;
            h0s[p ^ 1][j] = (f16)h0n;
            h0reg = h0n;
        }
        if (b1) BARRIER_LGKM();    // B2: new h0 visible (only layer-1 needs it now)

        // ---------------- Phase 1: layer-1 ih GEMV (hh done in phase 0) --------
        if (b1) {
            float pir = 0.f, piz = 0.f, pin = 0.f;
            if (!PRECOMP) gemv3p(W_ih1x, j, ksb, (const uint4*)x1sh[p], pir, piz, pin);
            gemv3p_pre(pf, ksb, (const uint4*)h0s[p ^ 1], pir, piz, pin);
            gemv3p_tail(W_ih1h, j, ksb, (const uint4*)h0s[p ^ 1], pir, piz, pin);
            rbuf[(0 * 4 + ks) * 256 + j] = pir;
            rbuf[(1 * 4 + ks) * 256 + j] = piz;
            rbuf[(2 * 4 + ks) * 256 + j] = pin;
            BARRIER_LGKM();        // B3
        }

        // ---------------- Epilogue 1 ----------------
        if (tid < 256) {
            float h1n;
            if (!b1) {
                h1n = dd1 ? c1v : h1reg;
            } else {
                float air = g1r, aiz = g1z, ain = g1n;
                float ahr = 0.f, ahz = 0.f, ahn = 0.f;
#pragma unroll
                for (int s = 0; s < 4; ++s) {
                    air += rbuf[(0 * 4 + s) * 256 + j];
                    aiz += rbuf[(1 * 4 + s) * 256 + j];
                    ain += rbuf[(2 * 4 + s) * 256 + j];
                }
                if (!dd1) {
#pragma unroll
                    for (int s = 0; s < 4; ++s) {
                        ahr += rbuf[(6 * 4 + s) * 256 + j];
                        ahz += rbuf[(7 * 4 + s) * 256 + j];
                        ahn += rbuf[(8 * 4 + s) * 256 + j];
                    }
                }
                const float h1cur = dd1 ? 0.0f : h1reg;
                const float r = sigm(air + ahr + sb1r);
                const float z = sigm(aiz + ahz + sb1z);
                const float n = tanhx(ain + bi1n + r * (ahn + bh1n));
                h1n = (1.0f - z) * n + z * h1cur;
            }
            out1[t * HH + j] = h1n;
            h1s[p ^ 1][j] = (f16)h1n;
            h1reg = h1n;
        }
        BARRIER_LGKM();            // B4: step boundary (h1s visible, rbuf free)
        p ^= 1;
    }
}

extern "C" void kernel_launch(void* const* d_in, const int* in_sizes, int n_in,
                              void* d_out, int out_size, void* d_ws, size_t ws_size,
                              hipStream_t stream) {
    const float* x0    = (const float*)d_in[0];
    const float* x1    = (const float*)d_in[1];
    const float* hx0   = (const float*)d_in[2];
    const float* hx1   = (const float*)d_in[3];
    const float* W_ih0 = (const float*)d_in[4];
    const float* W_hh0 = (const float*)d_in[5];
    const float* b_ih0 = (const float*)d_in[6];
    const float* b_hh0 = (const float*)d_in[7];
    const float* W_ih1 = (const float*)d_in[8];
    const float* W_hh1 = (const float*)d_in[9];
    const float* b_ih1 = (const float*)d_in[10];
    const float* b_hh1 = (const float*)d_in[11];
    const int* dx      = (const int*)d_in[12];
    const int* dxlz    = (const int*)d_in[13];
    float* out = (float*)d_out;

    const size_t sz_w  = (size_t)6 * MAT_U32 * sizeof(u32);         // 2.36 MB
    const size_t sz_gi = (size_t)2 * NBT * GI_STRIDE * sizeof(f16); // 201.3 MB
    const bool precomp = (d_ws != nullptr) && (ws_size >= sz_w + sz_gi);

    u32* ws = (u32*)d_ws;
    const int total = 6 * MAT_U32;
    pack_weights<<<(total + 255) / 256, 256, 0, stream>>>(W_ih0, W_hh0, W_ih1, W_hh1, ws);

    f16* gi = (f16*)((char*)d_ws + sz_w);
    if (precomp) {
        proj_gemm<<<2048, 256, 0, stream>>>(x0, x1, (const uint4*)ws, gi);
        hmgru_scan<true><<<BB, 1024, 0, stream>>>(
            x0, x1, hx0, hx1, b_ih0, b_hh0, b_ih1, b_hh1, dx, dxlz,
            (const uint4*)ws, gi, out);
    } else {
        hmgru_scan<false><<<BB, 1024, 0, stream>>>(
            x0, x1, hx0, hx1, b_ih0, b_hh0, b_ih1, b_hh1, dx, dxlz,
            (const uint4*)ws, gi, out);
    }
}

// Round 4
// 1792.377 us; speedup vs baseline: 2.7945x; 1.5313x over previous
//
#include <hip/hip_runtime.h>

// HMGRUV2: 2-layer masked GRU scan. B=256, T=256, L=2, IN=256, H=256 (f32 io).
// Round 8: un-bundle round-7. R7 regressed (2614us) via FETCH 56MB->2.13GB =
// scratch spill of the pf[9] register prefetch (36 VGPR live across two
// "memory" barriers at 64-VGPR alloc -> per-XCD scratch 4.7MB > 4MB L2 ->
// HBM thrash). This round keeps ONLY the zero-spill-risk pieces on the
// proven round-4 structure (1715us):
//  (a) lgkm-only barriers (no vmcnt(0) drain of out-stores/gi-loads).
//  (b) B2 conditional on b1.
//  (c) W_hh1@h1prev hoisted to phase 0 (independent of h0new; rbuf slots 6-8,
//      same per-gate accumulation order -> bitwise-identical results).
//  NO register-array prefetch.

#define BB 256
#define TT 256
#define HH 256
#define MAT_U32 98304   // u32 words per packed matrix (768*256/2)
#define MAT_U4  24576   // uint4 words per packed matrix
#define NBT 65536       // B*T
#define GI_STRIDE 768

typedef unsigned int u32;
typedef _Float16 f16;
typedef _Float16 f16x2 __attribute__((ext_vector_type(2)));
typedef _Float16 f16x4 __attribute__((ext_vector_type(4)));
typedef _Float16 f16x8 __attribute__((ext_vector_type(8)));
typedef float f32x4 __attribute__((ext_vector_type(4)));

#if defined(__has_builtin)
#  if __has_builtin(__builtin_amdgcn_fdot2)
#    define HAVE_FDOT2 1
#  endif
#endif

// LDS-only barrier: do NOT drain vmcnt (global loads/stores keep flowing;
// compiler still auto-waits vmcnt before any use of a load result).
#define BARRIER_LGKM() asm volatile("s_waitcnt lgkmcnt(0)\n\ts_barrier" ::: "memory")

__device__ __forceinline__ float dot2(f16x2 a, f16x2 b, float c) {
#ifdef HAVE_FDOT2
    return __builtin_amdgcn_fdot2(a, b, c, false);
#else
    return c + (float)a.x * (float)b.x + (float)a.y * (float)b.y;
#endif
}

union U4 { uint4 u; f16x2 h[4]; f16x8 v; };

__device__ __forceinline__ float sigm(float x) { return 1.0f / (1.0f + __expf(-x)); }
__device__ __forceinline__ float tanhx(float x) { return 1.0f - 2.0f / (__expf(2.0f * x) + 1.0f); }

// ---- pack f32 weights -> f16 pairs (round-3 proven layout) ----
// u32 flat (per matrix m) = k8*3072 + g*1024 + j*4 + q ; k = k8*8 + q*2 (+1).
__global__ void pack_weights(const float* __restrict__ W_ih0,
                             const float* __restrict__ W_hh0,
                             const float* __restrict__ W_ih1,
                             const float* __restrict__ W_hh1,
                             u32* __restrict__ ws) {
    int tid = blockIdx.x * 256 + threadIdx.x;
    if (tid >= 6 * MAT_U32) return;
    int m  = tid / MAT_U32;
    int r  = tid % MAT_U32;
    int k8 = r / 3072;
    int r2 = r % 3072;
    int g  = r2 / 1024;
    int r3 = r2 % 1024;
    int jj = r3 >> 2;
    int q  = r3 & 3;
    int k  = k8 * 8 + q * 2;
    int c  = g * 256 + jj;
    float lo, hi;
    switch (m) {
        case 0: lo = W_ih0[c * 512 + k];       hi = W_ih0[c * 512 + k + 1];   break;
        case 1: lo = W_ih0[c * 512 + 256 + k]; hi = W_ih0[c * 512 + 257 + k]; break;
        case 2: lo = W_hh0[c * 256 + k];       hi = W_hh0[c * 256 + k + 1];   break;
        case 3: lo = W_ih1[c * 512 + k];       hi = W_ih1[c * 512 + k + 1];   break;
        case 4: lo = W_ih1[c * 512 + 256 + k]; hi = W_ih1[c * 512 + 257 + k]; break;
        default: lo = W_hh1[c * 256 + k];      hi = W_hh1[c * 256 + k + 1];   break;
    }
    union { f16x2 h; u32 u; } pk;
    pk.h.x = (f16)lo;
    pk.h.y = (f16)hi;
    ws[tid] = pk.u;
}

// ---- MFMA GEMM: gi[layer][bt][m] = sum_k W_ihLx[m][k] * x[bt][k]  (f16) ----
__global__ __launch_bounds__(256, 2) void proj_gemm(
    const float* __restrict__ x0, const float* __restrict__ x1,
    const uint4* __restrict__ Wt, f16* __restrict__ gi) {
    const int nblk  = blockIdx.x & 1023;
    const int layer = blockIdx.x >> 10;
    const int bt0   = nblk * 64;
    const float4* __restrict__ X4 = (const float4*)(layer ? x1 : x0);
    const uint4*  __restrict__ W  = Wt + (layer ? 3 : 0) * MAT_U4;
    f16* __restrict__ giL = gi + (size_t)layer * NBT * GI_STRIDE;

    __shared__ __align__(16) f16 xs[64 * 264];  // 64 rows x 256 f16, +8 pad

    const int tid = threadIdx.x;
    for (int it = 0; it < 16; ++it) {
        int idx = it * 256 + tid;
        int r = idx >> 6, c4 = idx & 63;
        float4 v = X4[(size_t)(bt0 + r) * 64 + c4];
        union { f16x4 h; unsigned long long u; } pk;
        pk.h = (f16x4){(f16)v.x, (f16)v.y, (f16)v.z, (f16)v.w};
        *(unsigned long long*)((char*)xs + r * 528 + c4 * 8) = pk.u;
    }
    __syncthreads();

    const int wave = tid >> 6;
    const int lane = tid & 63;
    const int l16  = lane & 15;
    const int quad = lane >> 4;

    for (int i = 0; i < 12; ++i) {
        const int mt = i * 4 + wave;   // m-tile 0..47
        const int m0 = mt * 16;
        const int g  = m0 >> 8;
        const int j0 = m0 & 255;
        f16x8 afr[8];
#pragma unroll
        for (int kst = 0; kst < 8; ++kst) {
            U4 a;
            a.u = W[((kst * 4 + quad) * 3 + g) * 256 + (j0 + l16)];
            afr[kst] = a.v;
        }
#pragma unroll
        for (int nt = 0; nt < 4; ++nt) {
            const int n0 = nt * 16;
            f32x4 acc = {0.f, 0.f, 0.f, 0.f};
#pragma unroll
            for (int kst = 0; kst < 8; ++kst) {
                f16x8 bfr = *(const f16x8*)((const char*)xs +
                               (n0 + l16) * 528 + kst * 64 + quad * 16);
                acc = __builtin_amdgcn_mfma_f32_16x16x32_f16(afr[kst], bfr, acc, 0, 0, 0);
            }
            const int col = bt0 + n0 + l16;
            union { f16x4 h; unsigned long long u; } o;
            o.h = (f16x4){(f16)acc[0], (f16)acc[1], (f16)acc[2], (f16)acc[3]};
            *(unsigned long long*)(giL + (size_t)col * GI_STRIDE + m0 + quad * 4) = o.u;
        }
    }
}

// ---- split-K partial GEMV: 8 k8-groups (64 k) for unit j's three gates ----
__device__ __forceinline__ void gemv3p(const uint4* __restrict__ W, int j, int ksb,
                                       const uint4* __restrict__ s4,
                                       float& pr, float& pz, float& pn) {
#pragma unroll 4
    for (int i = 0; i < 8; ++i) {
        const int k8 = ksb + i;
        U4 sv, wr, wz, wn;
        sv.u = s4[k8];
        wr.u = W[(k8 * 3 + 0) * 256 + j];
        wz.u = W[(k8 * 3 + 1) * 256 + j];
        wn.u = W[(k8 * 3 + 2) * 256 + j];
#pragma unroll
        for (int q = 0; q < 4; ++q) {
            pr = dot2(wr.h[q], sv.h[q], pr);
            pz = dot2(wz.h[q], sv.h[q], pz);
            pn = dot2(wn.h[q], sv.h[q], pn);
        }
    }
}

template <bool PRECOMP>
__global__ __launch_bounds__(1024, 4) void hmgru_scan(
    const float* __restrict__ x0, const float* __restrict__ x1,
    const float* __restrict__ hx0, const float* __restrict__ hx1,
    const float* __restrict__ b_ih0, const float* __restrict__ b_hh0,
    const float* __restrict__ b_ih1, const float* __restrict__ b_hh1,
    const int* __restrict__ dx, const int* __restrict__ dxlz,
    const uint4* __restrict__ Wt, const f16* __restrict__ gi,
    float* __restrict__ out) {
    const int b   = blockIdx.x;
    const int tid = threadIdx.x;
    const int j   = tid & 255;
    const int ks  = tid >> 8;
    const int ksb = ks * 8;

    const uint4* W_ih0x = Wt + 0 * MAT_U4;
    const uint4* W_ih0h = Wt + 1 * MAT_U4;
    const uint4* W_hh0  = Wt + 2 * MAT_U4;
    const uint4* W_ih1x = Wt + 3 * MAT_U4;
    const uint4* W_ih1h = Wt + 4 * MAT_U4;
    const uint4* W_hh1  = Wt + 5 * MAT_U4;
    const f16* gi0 = gi;
    const f16* gi1 = gi + (size_t)NBT * GI_STRIDE;

    __shared__ __align__(16) f16 h0s[2][256], h1s[2][256];
    __shared__ __align__(16) f16 x0sh[2][256], x1sh[2][256];  // fallback only
    __shared__ float rbuf[9 * 4 * 256];   // c0-5 layer partials, c6-8 hh1-early
    __shared__ int m0s[TT], mAs[TT], mBs[TT];

    // biases: fold r/z into sums; n-gate needs ih/hh parts separate
    const float sb0r = b_ih0[j] + b_hh0[j];
    const float sb0z = b_ih0[256 + j] + b_hh0[256 + j];
    const float bi0n = b_ih0[512 + j], bh0n = b_hh0[512 + j];
    const float sb1r = b_ih1[j] + b_hh1[j];
    const float sb1z = b_ih1[256 + j] + b_hh1[256 + j];
    const float bi1n = b_ih1[512 + j], bh1n = b_hh1[512 + j];

    // (b1=0, dd1=1): bias-only GRU constant.
    const float c1r = sigm(sb1r);
    const float c1z = sigm(sb1z);
    const float c1n = tanhx(bi1n + c1r * bh1n);
    const float c1v = (1.0f - c1z) * c1n;

    float h0reg = hx0[b * HH + j];
    float h1reg = hx1[b * HH + j];

    const int* dxb  = dx + b * 2 * TT;
    const int* dlzb = dxlz + b * TT;
    const float* x0b = x0 + (size_t)b * TT * 256;
    const float* x1b = x1 + (size_t)b * TT * 256;
    float* out0 = out + (size_t)b * TT * HH;
    float* out1 = out + (size_t)(BB + b) * TT * HH;

    if (tid < 256) {
        h0s[0][j] = (f16)h0reg;
        h1s[0][j] = (f16)h1reg;
        if (!PRECOMP) {
            x0sh[0][j] = (f16)x0b[j];
            x1sh[0][j] = (f16)x1b[j];
        }
        m0s[j] = dlzb[j];
        mAs[j] = dxb[j];
        mBs[j] = dxb[TT + j];
    }
    BARRIER_LGKM();

    int p = 0;
    for (int t = 0; t < TT; ++t) {
        const int b0  = m0s[t];
        const int b1  = mAs[t];
        const int dd0 = t ? mAs[t - 1] : 0;
        const int dd1 = t ? mBs[t - 1] : 0;
        const int bt  = b * TT + t;

        // fallback: prefetch x(t+1) into the other buffer
        if (!PRECOMP && tid < 256 && (t + 1) < TT) {
            x0sh[p ^ 1][j] = (f16)x0b[(t + 1) * 256 + j];
            x1sh[p ^ 1][j] = (f16)x1b[(t + 1) * 256 + j];
        }
        // precomp: prefetch gi rows into registers (hidden behind GEMVs;
        // with lgkm-only barriers these stay in flight until the epilogues)
        float g0r = 0.f, g0z = 0.f, g0n = 0.f, g1r = 0.f, g1z = 0.f, g1n = 0.f;
        if (PRECOMP && tid < 256) {
            if (b0) {
                const f16* pg = gi0 + (size_t)bt * GI_STRIDE;
                g0r = (float)pg[j]; g0z = (float)pg[256 + j]; g0n = (float)pg[512 + j];
            }
            if (b1) {
                const f16* pg = gi1 + (size_t)bt * GI_STRIDE;
                g1r = (float)pg[j]; g1z = (float)pg[256 + j]; g1n = (float)pg[512 + j];
            }
        }

        const int l0g  = b0 | dd0;
        const int hh1e = b1 & (dd1 ^ 1);   // W_hh1 hoisted into phase 0

        // ---------------- Phase 0: layer-0 GEMVs + hh1-early ----------------
        if (l0g) {
            float pir = 0.f, piz = 0.f, pin = 0.f, phr = 0.f, phz = 0.f, phn = 0.f;
            if (!PRECOMP && b0) gemv3p(W_ih0x, j, ksb, (const uint4*)x0sh[p], pir, piz, pin);
            if (dd0)            gemv3p(W_ih0h, j, ksb, (const uint4*)h1s[p], pir, piz, pin);
            if (!dd0)           gemv3p(W_hh0,  j, ksb, (const uint4*)h0s[p], phr, phz, phn);
            rbuf[(0 * 4 + ks) * 256 + j] = pir;
            rbuf[(1 * 4 + ks) * 256 + j] = piz;
            rbuf[(2 * 4 + ks) * 256 + j] = pin;
            rbuf[(3 * 4 + ks) * 256 + j] = phr;
            rbuf[(4 * 4 + ks) * 256 + j] = phz;
            rbuf[(5 * 4 + ks) * 256 + j] = phn;
        }
        if (hh1e) {
            float qhr = 0.f, qhz = 0.f, qhn = 0.f;
            gemv3p(W_hh1, j, ksb, (const uint4*)h1s[p], qhr, qhz, qhn);
            rbuf[(6 * 4 + ks) * 256 + j] = qhr;
            rbuf[(7 * 4 + ks) * 256 + j] = qhz;
            rbuf[(8 * 4 + ks) * 256 + j] = qhn;
        }
        if (l0g) BARRIER_LGKM();   // B1: layer-0 partials visible

        // ---------------- Epilogue 0 ----------------
        if (tid < 256) {
            float h0n;
            if (!l0g) {
                h0n = h0reg;  // pure carry
            } else {
                float air = g0r, aiz = g0z, ain = g0n;
                float ahr = 0.f, ahz = 0.f, ahn = 0.f;
#pragma unroll
                for (int s = 0; s < 4; ++s) {
                    air += rbuf[(0 * 4 + s) * 256 + j];
                    aiz += rbuf[(1 * 4 + s) * 256 + j];
                    ain += rbuf[(2 * 4 + s) * 256 + j];
                    ahr += rbuf[(3 * 4 + s) * 256 + j];
                    ahz += rbuf[(4 * 4 + s) * 256 + j];
                    ahn += rbuf[(5 * 4 + s) * 256 + j];
                }
                const float h0cur = dd0 ? 0.0f : h0reg;
                const float r = sigm(air + ahr + sb0r);
                const float z = sigm(aiz + ahz + sb0z);
                const float n = tanhx(ain + bi0n + r * (ahn + bh0n));
                h0n = (1.0f - z) * n + z * h0cur;
            }
            out0[t * HH + j] = h0n;
            h0s[p ^ 1][j] = (f16)h0n;
            h0reg = h0n;
        }
        if (b1) BARRIER_LGKM();    // B2: new h0 visible (only layer-1 needs it)

        // ---------------- Phase 1: layer-1 ih GEMVs (hh done in phase 0) ----
        if (b1) {
            float pir = 0.f, piz = 0.f, pin = 0.f;
            if (!PRECOMP) gemv3p(W_ih1x, j, ksb, (const uint4*)x1sh[p], pir, piz, pin);
            gemv3p(W_ih1h, j, ksb, (const uint4*)h0s[p ^ 1], pir, piz, pin);  // new h0
            rbuf[(0 * 4 + ks) * 256 + j] = pir;
            rbuf[(1 * 4 + ks) * 256 + j] = piz;
            rbuf[(2 * 4 + ks) * 256 + j] = pin;
            BARRIER_LGKM();        // B3
        }

        // ---------------- Epilogue 1 ----------------
        if (tid < 256) {
            float h1n;
            if (!b1) {
                h1n = dd1 ? c1v : h1reg;
            } else {
                float air = g1r, aiz = g1z, ain = g1n;
                float ahr = 0.f, ahz = 0.f, ahn = 0.f;
#pragma unroll
                for (int s = 0; s < 4; ++s) {
                    air += rbuf[(0 * 4 + s) * 256 + j];
                    aiz += rbuf[(1 * 4 + s) * 256 + j];
                    ain += rbuf[(2 * 4 + s) * 256 + j];
                }
                if (!dd1) {
#pragma unroll
                    for (int s = 0; s < 4; ++s) {
                        ahr += rbuf[(6 * 4 + s) * 256 + j];
                        ahz += rbuf[(7 * 4 + s) * 256 + j];
                        ahn += rbuf[(8 * 4 + s) * 256 + j];
                    }
                }
                const float h1cur = dd1 ? 0.0f : h1reg;
                const float r = sigm(air + ahr + sb1r);
                const float z = sigm(aiz + ahz + sb1z);
                const float n = tanhx(ain + bi1n + r * (ahn + bh1n));
                h1n = (1.0f - z) * n + z * h1cur;
            }
            out1[t * HH + j] = h1n;
            h1s[p ^ 1][j] = (f16)h1n;
            h1reg = h1n;
        }
        BARRIER_LGKM();            // B4: step boundary (h1s visible, rbuf free)
        p ^= 1;
    }
}

extern "C" void kernel_launch(void* const* d_in, const int* in_sizes, int n_in,
                              void* d_out, int out_size, void* d_ws, size_t ws_size,
                              hipStream_t stream) {
    const float* x0    = (const float*)d_in[0];
    const float* x1    = (const float*)d_in[1];
    const float* hx0   = (const float*)d_in[2];
    const float* hx1   = (const float*)d_in[3];
    const float* W_ih0 = (const float*)d_in[4];
    const float* W_hh0 = (const float*)d_in[5];
    const float* b_ih0 = (const float*)d_in[6];
    const float* b_hh0 = (const float*)d_in[7];
    const float* W_ih1 = (const float*)d_in[8];
    const float* W_hh1 = (const float*)d_in[9];
    const float* b_ih1 = (const float*)d_in[10];
    const float* b_hh1 = (const float*)d_in[11];
    const int* dx      = (const int*)d_in[12];
    const int* dxlz    = (const int*)d_in[13];
    float* out = (float*)d_out;

    const size_t sz_w  = (size_t)6 * MAT_U32 * sizeof(u32);         // 2.36 MB
    const size_t sz_gi = (size_t)2 * NBT * GI_STRIDE * sizeof(f16); // 201.3 MB
    const bool precomp = (d_ws != nullptr) && (ws_size >= sz_w + sz_gi);

    u32* ws = (u32*)d_ws;
    const int total = 6 * MAT_U32;
    pack_weights<<<(total + 255) / 256, 256, 0, stream>>>(W_ih0, W_hh0, W_ih1, W_hh1, ws);

    f16* gi = (f16*)((char*)d_ws + sz_w);
    if (precomp) {
        proj_gemm<<<2048, 256, 0, stream>>>(x0, x1, (const uint4*)ws, gi);
        hmgru_scan<true><<<BB, 1024, 0, stream>>>(
            x0, x1, hx0, hx1, b_ih0, b_hh0, b_ih1, b_hh1, dx, dxlz,
            (const uint4*)ws, gi, out);
    } else {
        hmgru_scan<false><<<BB, 1024, 0, stream>>>(
            x0, x1, hx0, hx1, b_ih0, b_hh0, b_ih1, b_hh1, dx, dxlz,
            (const uint4*)ws, gi, out);
    }
}

// Round 5
// 1687.881 us; speedup vs baseline: 2.9675x; 1.0619x over previous
//
#include <hip/hip_runtime.h>

// HMGRUV2: 2-layer masked GRU scan. B=256, T=256, L=2, IN=256, H=256 (f32 io).
// Round 9: R8 (lgkm-only barriers + cond B2 + hh1 hoist) = 1671us scan, best.
// Model: step = serial L2 weight stream E[590KB] at ~56-60 B/cyc/CU (~10k cyc)
// + epilogues/barriers (~2.2k) + misc. Only remaining lever: fewer L2 bytes.
// This round: LDS WEIGHT CACHE. Block uses 42KB of 160KB LDS; cache 96KB of
// W_ih1h (k8 groups ksb+0,ksb+1 per slice = 25% of the matrix) at kernel
// start. Phase-1 (the strictly-serialized post-h0new stream) drops 393->295KB
// from L2; cached part reads from the LDS pipe concurrently. Accumulation
// order unchanged -> bitwise-identical output (absmax must stay 0.00390625).

#define BB 256
#define TT 256
#define HH 256
#define MAT_U32 98304   // u32 words per packed matrix (768*256/2)
#define MAT_U4  24576   // uint4 words per packed matrix
#define NBT 65536       // B*T
#define GI_STRIDE 768

typedef unsigned int u32;
typedef _Float16 f16;
typedef _Float16 f16x2 __attribute__((ext_vector_type(2)));
typedef _Float16 f16x4 __attribute__((ext_vector_type(4)));
typedef _Float16 f16x8 __attribute__((ext_vector_type(8)));
typedef float f32x4 __attribute__((ext_vector_type(4)));

#if defined(__has_builtin)
#  if __has_builtin(__builtin_amdgcn_fdot2)
#    define HAVE_FDOT2 1
#  endif
#endif

// LDS-only barrier: do NOT drain vmcnt (global loads/stores keep flowing;
// compiler still auto-waits vmcnt before any use of a load result).
#define BARRIER_LGKM() asm volatile("s_waitcnt lgkmcnt(0)\n\ts_barrier" ::: "memory")

__device__ __forceinline__ float dot2(f16x2 a, f16x2 b, float c) {
#ifdef HAVE_FDOT2
    return __builtin_amdgcn_fdot2(a, b, c, false);
#else
    return c + (float)a.x * (float)b.x + (float)a.y * (float)b.y;
#endif
}

union U4 { uint4 u; f16x2 h[4]; f16x8 v; };

__device__ __forceinline__ float sigm(float x) { return 1.0f / (1.0f + __expf(-x)); }
__device__ __forceinline__ float tanhx(float x) { return 1.0f - 2.0f / (__expf(2.0f * x) + 1.0f); }

// ---- pack f32 weights -> f16 pairs (round-3 proven layout) ----
// u32 flat (per matrix m) = k8*3072 + g*1024 + j*4 + q ; k = k8*8 + q*2 (+1).
__global__ void pack_weights(const float* __restrict__ W_ih0,
                             const float* __restrict__ W_hh0,
                             const float* __restrict__ W_ih1,
                             const float* __restrict__ W_hh1,
                             u32* __restrict__ ws) {
    int tid = blockIdx.x * 256 + threadIdx.x;
    if (tid >= 6 * MAT_U32) return;
    int m  = tid / MAT_U32;
    int r  = tid % MAT_U32;
    int k8 = r / 3072;
    int r2 = r % 3072;
    int g  = r2 / 1024;
    int r3 = r2 % 1024;
    int jj = r3 >> 2;
    int q  = r3 & 3;
    int k  = k8 * 8 + q * 2;
    int c  = g * 256 + jj;
    float lo, hi;
    switch (m) {
        case 0: lo = W_ih0[c * 512 + k];       hi = W_ih0[c * 512 + k + 1];   break;
        case 1: lo = W_ih0[c * 512 + 256 + k]; hi = W_ih0[c * 512 + 257 + k]; break;
        case 2: lo = W_hh0[c * 256 + k];       hi = W_hh0[c * 256 + k + 1];   break;
        case 3: lo = W_ih1[c * 512 + k];       hi = W_ih1[c * 512 + k + 1];   break;
        case 4: lo = W_ih1[c * 512 + 256 + k]; hi = W_ih1[c * 512 + 257 + k]; break;
        default: lo = W_hh1[c * 256 + k];      hi = W_hh1[c * 256 + k + 1];   break;
    }
    union { f16x2 h; u32 u; } pk;
    pk.h.x = (f16)lo;
    pk.h.y = (f16)hi;
    ws[tid] = pk.u;
}

// ---- MFMA GEMM: gi[layer][bt][m] = sum_k W_ihLx[m][k] * x[bt][k]  (f16) ----
__global__ __launch_bounds__(256, 2) void proj_gemm(
    const float* __restrict__ x0, const float* __restrict__ x1,
    const uint4* __restrict__ Wt, f16* __restrict__ gi) {
    const int nblk  = blockIdx.x & 1023;
    const int layer = blockIdx.x >> 10;
    const int bt0   = nblk * 64;
    const float4* __restrict__ X4 = (const float4*)(layer ? x1 : x0);
    const uint4*  __restrict__ W  = Wt + (layer ? 3 : 0) * MAT_U4;
    f16* __restrict__ giL = gi + (size_t)layer * NBT * GI_STRIDE;

    __shared__ __align__(16) f16 xs[64 * 264];  // 64 rows x 256 f16, +8 pad

    const int tid = threadIdx.x;
    for (int it = 0; it < 16; ++it) {
        int idx = it * 256 + tid;
        int r = idx >> 6, c4 = idx & 63;
        float4 v = X4[(size_t)(bt0 + r) * 64 + c4];
        union { f16x4 h; unsigned long long u; } pk;
        pk.h = (f16x4){(f16)v.x, (f16)v.y, (f16)v.z, (f16)v.w};
        *(unsigned long long*)((char*)xs + r * 528 + c4 * 8) = pk.u;
    }
    __syncthreads();

    const int wave = tid >> 6;
    const int lane = tid & 63;
    const int l16  = lane & 15;
    const int quad = lane >> 4;

    for (int i = 0; i < 12; ++i) {
        const int mt = i * 4 + wave;   // m-tile 0..47
        const int m0 = mt * 16;
        const int g  = m0 >> 8;
        const int j0 = m0 & 255;
        f16x8 afr[8];
#pragma unroll
        for (int kst = 0; kst < 8; ++kst) {
            U4 a;
            a.u = W[((kst * 4 + quad) * 3 + g) * 256 + (j0 + l16)];
            afr[kst] = a.v;
        }
#pragma unroll
        for (int nt = 0; nt < 4; ++nt) {
            const int n0 = nt * 16;
            f32x4 acc = {0.f, 0.f, 0.f, 0.f};
#pragma unroll
            for (int kst = 0; kst < 8; ++kst) {
                f16x8 bfr = *(const f16x8*)((const char*)xs +
                               (n0 + l16) * 528 + kst * 64 + quad * 16);
                acc = __builtin_amdgcn_mfma_f32_16x16x32_f16(afr[kst], bfr, acc, 0, 0, 0);
            }
            const int col = bt0 + n0 + l16;
            union { f16x4 h; unsigned long long u; } o;
            o.h = (f16x4){(f16)acc[0], (f16)acc[1], (f16)acc[2], (f16)acc[3]};
            *(unsigned long long*)(giL + (size_t)col * GI_STRIDE + m0 + quad * 4) = o.u;
        }
    }
}

// ---- split-K partial GEMV: 8 k8-groups (64 k) for unit j's three gates ----
__device__ __forceinline__ void gemv3p(const uint4* __restrict__ W, int j, int ksb,
                                       const uint4* __restrict__ s4,
                                       float& pr, float& pz, float& pn) {
#pragma unroll 4
    for (int i = 0; i < 8; ++i) {
        const int k8 = ksb + i;
        U4 sv, wr, wz, wn;
        sv.u = s4[k8];
        wr.u = W[(k8 * 3 + 0) * 256 + j];
        wz.u = W[(k8 * 3 + 1) * 256 + j];
        wn.u = W[(k8 * 3 + 2) * 256 + j];
#pragma unroll
        for (int q = 0; q < 4; ++q) {
            pr = dot2(wr.h[q], sv.h[q], pr);
            pz = dot2(wz.h[q], sv.h[q], pz);
            pn = dot2(wn.h[q], sv.h[q], pn);
        }
    }
}

// ---- cached variant: k8 = ksb+0, ksb+1 come from the LDS weight cache ----
// wc points at this slice's cache: [i(0..1)][gate(0..2)][j] uint4.
// Same accumulation order as gemv3p (i ascending) -> bitwise identical.
__device__ __forceinline__ void gemv3p_c2(const uint4* __restrict__ W,
                                          const uint4* __restrict__ wc,
                                          int j, int ksb,
                                          const uint4* __restrict__ s4,
                                          float& pr, float& pz, float& pn) {
#pragma unroll
    for (int i = 0; i < 2; ++i) {
        U4 sv, wr, wz, wn;
        sv.u = s4[ksb + i];
        wr.u = wc[(i * 3 + 0) * 256 + j];
        wz.u = wc[(i * 3 + 1) * 256 + j];
        wn.u = wc[(i * 3 + 2) * 256 + j];
#pragma unroll
        for (int q = 0; q < 4; ++q) {
            pr = dot2(wr.h[q], sv.h[q], pr);
            pz = dot2(wz.h[q], sv.h[q], pz);
            pn = dot2(wn.h[q], sv.h[q], pn);
        }
    }
#pragma unroll 3
    for (int i = 2; i < 8; ++i) {
        const int k8 = ksb + i;
        U4 sv, wr, wz, wn;
        sv.u = s4[k8];
        wr.u = W[(k8 * 3 + 0) * 256 + j];
        wz.u = W[(k8 * 3 + 1) * 256 + j];
        wn.u = W[(k8 * 3 + 2) * 256 + j];
#pragma unroll
        for (int q = 0; q < 4; ++q) {
            pr = dot2(wr.h[q], sv.h[q], pr);
            pz = dot2(wz.h[q], sv.h[q], pz);
            pn = dot2(wn.h[q], sv.h[q], pn);
        }
    }
}

template <bool PRECOMP>
__global__ __launch_bounds__(1024, 4) void hmgru_scan(
    const float* __restrict__ x0, const float* __restrict__ x1,
    const float* __restrict__ hx0, const float* __restrict__ hx1,
    const float* __restrict__ b_ih0, const float* __restrict__ b_hh0,
    const float* __restrict__ b_ih1, const float* __restrict__ b_hh1,
    const int* __restrict__ dx, const int* __restrict__ dxlz,
    const uint4* __restrict__ Wt, const f16* __restrict__ gi,
    float* __restrict__ out) {
    const int b   = blockIdx.x;
    const int tid = threadIdx.x;
    const int j   = tid & 255;
    const int ks  = tid >> 8;
    const int ksb = ks * 8;

    const uint4* W_ih0x = Wt + 0 * MAT_U4;
    const uint4* W_ih0h = Wt + 1 * MAT_U4;
    const uint4* W_hh0  = Wt + 2 * MAT_U4;
    const uint4* W_ih1x = Wt + 3 * MAT_U4;
    const uint4* W_ih1h = Wt + 4 * MAT_U4;
    const uint4* W_hh1  = Wt + 5 * MAT_U4;
    const f16* gi0 = gi;
    const f16* gi1 = gi + (size_t)NBT * GI_STRIDE;

    __shared__ __align__(16) f16 h0s[2][256], h1s[2][256];
    __shared__ __align__(16) f16 x0sh[2][256], x1sh[2][256];  // fallback only
    __shared__ float rbuf[9 * 4 * 256];   // c0-5 layer partials, c6-8 hh1-early
    __shared__ int m0s[TT], mAs[TT], mBs[TT];
    // 96KB LDS weight cache: W_ih1h k8 groups {ksb+0, ksb+1} per slice.
    // layout [ks][i][gate][j] uint4
    __shared__ __align__(16) uint4 wcache[4 * 2 * 3 * 256];

    // fill the weight cache (6 uint4 per thread; visible after init barrier)
    {
#pragma unroll
        for (int i = 0; i < 2; ++i)
#pragma unroll
            for (int g = 0; g < 3; ++g)
                wcache[((ks * 2 + i) * 3 + g) * 256 + j] =
                    W_ih1h[((ksb + i) * 3 + g) * 256 + j];
    }

    // biases: fold r/z into sums; n-gate needs ih/hh parts separate
    const float sb0r = b_ih0[j] + b_hh0[j];
    const float sb0z = b_ih0[256 + j] + b_hh0[256 + j];
    const float bi0n = b_ih0[512 + j], bh0n = b_hh0[512 + j];
    const float sb1r = b_ih1[j] + b_hh1[j];
    const float sb1z = b_ih1[256 + j] + b_hh1[256 + j];
    const float bi1n = b_ih1[512 + j], bh1n = b_hh1[512 + j];

    // (b1=0, dd1=1): bias-only GRU constant.
    const float c1r = sigm(sb1r);
    const float c1z = sigm(sb1z);
    const float c1n = tanhx(bi1n + c1r * bh1n);
    const float c1v = (1.0f - c1z) * c1n;

    float h0reg = hx0[b * HH + j];
    float h1reg = hx1[b * HH + j];

    const int* dxb  = dx + b * 2 * TT;
    const int* dlzb = dxlz + b * TT;
    const float* x0b = x0 + (size_t)b * TT * 256;
    const float* x1b = x1 + (size_t)b * TT * 256;
    float* out0 = out + (size_t)b * TT * HH;
    float* out1 = out + (size_t)(BB + b) * TT * HH;

    if (tid < 256) {
        h0s[0][j] = (f16)h0reg;
        h1s[0][j] = (f16)h1reg;
        if (!PRECOMP) {
            x0sh[0][j] = (f16)x0b[j];
            x1sh[0][j] = (f16)x1b[j];
        }
        m0s[j] = dlzb[j];
        mAs[j] = dxb[j];
        mBs[j] = dxb[TT + j];
    }
    BARRIER_LGKM();

    int p = 0;
    for (int t = 0; t < TT; ++t) {
        const int b0  = m0s[t];
        const int b1  = mAs[t];
        const int dd0 = t ? mAs[t - 1] : 0;
        const int dd1 = t ? mBs[t - 1] : 0;
        const int bt  = b * TT + t;

        // fallback: prefetch x(t+1) into the other buffer
        if (!PRECOMP && tid < 256 && (t + 1) < TT) {
            x0sh[p ^ 1][j] = (f16)x0b[(t + 1) * 256 + j];
            x1sh[p ^ 1][j] = (f16)x1b[(t + 1) * 256 + j];
        }
        // precomp: prefetch gi rows into registers (hidden behind GEMVs;
        // with lgkm-only barriers these stay in flight until the epilogues)
        float g0r = 0.f, g0z = 0.f, g0n = 0.f, g1r = 0.f, g1z = 0.f, g1n = 0.f;
        if (PRECOMP && tid < 256) {
            if (b0) {
                const f16* pg = gi0 + (size_t)bt * GI_STRIDE;
                g0r = (float)pg[j]; g0z = (float)pg[256 + j]; g0n = (float)pg[512 + j];
            }
            if (b1) {
                const f16* pg = gi1 + (size_t)bt * GI_STRIDE;
                g1r = (float)pg[j]; g1z = (float)pg[256 + j]; g1n = (float)pg[512 + j];
            }
        }

        const int l0g  = b0 | dd0;
        const int hh1e = b1 & (dd1 ^ 1);   // W_hh1 hoisted into phase 0

        // ---------------- Phase 0: layer-0 GEMVs + hh1-early ----------------
        if (l0g) {
            float pir = 0.f, piz = 0.f, pin = 0.f, phr = 0.f, phz = 0.f, phn = 0.f;
            if (!PRECOMP && b0) gemv3p(W_ih0x, j, ksb, (const uint4*)x0sh[p], pir, piz, pin);
            if (dd0)            gemv3p(W_ih0h, j, ksb, (const uint4*)h1s[p], pir, piz, pin);
            if (!dd0)           gemv3p(W_hh0,  j, ksb, (const uint4*)h0s[p], phr, phz, phn);
            rbuf[(0 * 4 + ks) * 256 + j] = pir;
            rbuf[(1 * 4 + ks) * 256 + j] = piz;
            rbuf[(2 * 4 + ks) * 256 + j] = pin;
            rbuf[(3 * 4 + ks) * 256 + j] = phr;
            rbuf[(4 * 4 + ks) * 256 + j] = phz;
            rbuf[(5 * 4 + ks) * 256 + j] = phn;
        }
        if (hh1e) {
            float qhr = 0.f, qhz = 0.f, qhn = 0.f;
            gemv3p(W_hh1, j, ksb, (const uint4*)h1s[p], qhr, qhz, qhn);
            rbuf[(6 * 4 + ks) * 256 + j] = qhr;
            rbuf[(7 * 4 + ks) * 256 + j] = qhz;
            rbuf[(8 * 4 + ks) * 256 + j] = qhn;
        }
        if (l0g) BARRIER_LGKM();   // B1: layer-0 partials visible

        // ---------------- Epilogue 0 ----------------
        if (tid < 256) {
            float h0n;
            if (!l0g) {
                h0n = h0reg;  // pure carry
            } else {
                float air = g0r, aiz = g0z, ain = g0n;
                float ahr = 0.f, ahz = 0.f, ahn = 0.f;
#pragma unroll
                for (int s = 0; s < 4; ++s) {
                    air += rbuf[(0 * 4 + s) * 256 + j];
                    aiz += rbuf[(1 * 4 + s) * 256 + j];
                    ain += rbuf[(2 * 4 + s) * 256 + j];
                    ahr += rbuf[(3 * 4 + s) * 256 + j];
                    ahz += rbuf[(4 * 4 + s) * 256 + j];
                    ahn += rbuf[(5 * 4 + s) * 256 + j];
                }
                const float h0cur = dd0 ? 0.0f : h0reg;
                const float r = sigm(air + ahr + sb0r);
                const float z = sigm(aiz + ahz + sb0z);
                const float n = tanhx(ain + bi0n + r * (ahn + bh0n));
                h0n = (1.0f - z) * n + z * h0cur;
            }
            out0[t * HH + j] = h0n;
            h0s[p ^ 1][j] = (f16)h0n;
            h0reg = h0n;
        }
        if (b1) BARRIER_LGKM();    // B2: new h0 visible (only layer-1 needs it)

        // ---------------- Phase 1: layer-1 ih GEMVs (hh done in phase 0) ----
        if (b1) {
            float pir = 0.f, piz = 0.f, pin = 0.f;
            if (!PRECOMP) gemv3p(W_ih1x, j, ksb, (const uint4*)x1sh[p], pir, piz, pin);
            gemv3p_c2(W_ih1h, wcache + (size_t)ks * 2 * 3 * 256, j, ksb,
                      (const uint4*)h0s[p ^ 1], pir, piz, pin);  // new h0
            rbuf[(0 * 4 + ks) * 256 + j] = pir;
            rbuf[(1 * 4 + ks) * 256 + j] = piz;
            rbuf[(2 * 4 + ks) * 256 + j] = pin;
            BARRIER_LGKM();        // B3
        }

        // ---------------- Epilogue 1 ----------------
        if (tid < 256) {
            float h1n;
            if (!b1) {
                h1n = dd1 ? c1v : h1reg;
            } else {
                float air = g1r, aiz = g1z, ain = g1n;
                float ahr = 0.f, ahz = 0.f, ahn = 0.f;
#pragma unroll
                for (int s = 0; s < 4; ++s) {
                    air += rbuf[(0 * 4 + s) * 256 + j];
                    aiz += rbuf[(1 * 4 + s) * 256 + j];
                    ain += rbuf[(2 * 4 + s) * 256 + j];
                }
                if (!dd1) {
#pragma unroll
                    for (int s = 0; s < 4; ++s) {
                        ahr += rbuf[(6 * 4 + s) * 256 + j];
                        ahz += rbuf[(7 * 4 + s) * 256 + j];
                        ahn += rbuf[(8 * 4 + s) * 256 + j];
                    }
                }
                const float h1cur = dd1 ? 0.0f : h1reg;
                const float r = sigm(air + ahr + sb1r);
                const float z = sigm(aiz + ahz + sb1z);
                const float n = tanhx(ain + bi1n + r * (ahn + bh1n));
                h1n = (1.0f - z) * n + z * h1cur;
            }
            out1[t * HH + j] = h1n;
            h1s[p ^ 1][j] = (f16)h1n;
            h1reg = h1n;
        }
        BARRIER_LGKM();            // B4: step boundary (h1s visible, rbuf free)
        p ^= 1;
    }
}

extern "C" void kernel_launch(void* const* d_in, const int* in_sizes, int n_in,
                              void* d_out, int out_size, void* d_ws, size_t ws_size,
                              hipStream_t stream) {
    const float* x0    = (const float*)d_in[0];
    const float* x1    = (const float*)d_in[1];
    const float* hx0   = (const float*)d_in[2];
    const float* hx1   = (const float*)d_in[3];
    const float* W_ih0 = (const float*)d_in[4];
    const float* W_hh0 = (const float*)d_in[5];
    const float* b_ih0 = (const float*)d_in[6];
    const float* b_hh0 = (const float*)d_in[7];
    const float* W_ih1 = (const float*)d_in[8];
    const float* W_hh1 = (const float*)d_in[9];
    const float* b_ih1 = (const float*)d_in[10];
    const float* b_hh1 = (const float*)d_in[11];
    const int* dx      = (const int*)d_in[12];
    const int* dxlz    = (const int*)d_in[13];
    float* out = (float*)d_out;

    const size_t sz_w  = (size_t)6 * MAT_U32 * sizeof(u32);         // 2.36 MB
    const size_t sz_gi = (size_t)2 * NBT * GI_STRIDE * sizeof(f16); // 201.3 MB
    const bool precomp = (d_ws != nullptr) && (ws_size >= sz_w + sz_gi);

    u32* ws = (u32*)d_ws;
    const int total = 6 * MAT_U32;
    pack_weights<<<(total + 255) / 256, 256, 0, stream>>>(W_ih0, W_hh0, W_ih1, W_hh1, ws);

    f16* gi = (f16*)((char*)d_ws + sz_w);
    if (precomp) {
        proj_gemm<<<2048, 256, 0, stream>>>(x0, x1, (const uint4*)ws, gi);
        hmgru_scan<true><<<BB, 1024, 0, stream>>>(
            x0, x1, hx0, hx1, b_ih0, b_hh0, b_ih1, b_hh1, dx, dxlz,
            (const uint4*)ws, gi, out);
    } else {
        hmgru_scan<false><<<BB, 1024, 0, stream>>>(
            x0, x1, hx0, hx1, b_ih0, b_hh0, b_ih1, b_hh1, dx, dxlz,
            (const uint4*)ws, gi, out);
    }
}